// Round 1
// baseline (337.618 us; speedup 1.0000x reference)
//
#include <hip/hip_runtime.h>
#include <math.h>

// NoisyTopkRouter: B=8,S=4096,D=1024,E=64,k=2
// Fused GEMM [M,1024] x [1024,128] (Wl ++ Wn) + softplus-noise + softmax + top2.
// fp32 vector-ALU compute (no fp32 MFMA on CDNA4; bf16 would flip top-k order).

#define DIM 1024
#define NEXP 64
#define NOUT 128           // 64 logits + 64 noise-std pre-activations
#define TOK_PER_BLK 64
#define KB 32

__global__ __launch_bounds__(256, 2)
void noisy_topk_router_kernel(const float* __restrict__ h,
                              const float* __restrict__ Wl,
                              const float* __restrict__ bl,
                              const float* __restrict__ Wn,
                              const float* __restrict__ bn,
                              const float* __restrict__ noise,
                              float* __restrict__ out,
                              int M)
{
    // staging: hs [KB][64] = 2048 f, ws [KB][128] = 4096 f  (24 KB)
    // epilogue reuses as Cs [64][128] = 8192 f (32 KB)
    __shared__ float smem[TOK_PER_BLK * NOUT];
    float* hs = smem;
    float* ws = smem + KB * TOK_PER_BLK;

    const int tid = threadIdx.x;
    const int tx = tid & 15;    // expert-octet: e = tx*8 + j
    const int ty = tid >> 4;    // token-quad:   t = ty*4 + i
    const int tok0 = blockIdx.x * TOK_PER_BLK;

    float acc[4][8];
#pragma unroll
    for (int i = 0; i < 4; i++)
#pragma unroll
        for (int j = 0; j < 8; j++) acc[i][j] = 0.f;

    for (int kc = 0; kc < DIM; kc += KB) {
        // ---- stage h tile: 64 tok x 32 k = 512 float4 ----
#pragma unroll
        for (int r = 0; r < 2; r++) {
            int q = tid + r * 256;
            int tok = q >> 3;          // 8 float4 per token row
            int kq = q & 7;
            float4 v = *(const float4*)(h + (size_t)(tok0 + tok) * DIM + kc + kq * 4);
            hs[(kq * 4 + 0) * 64 + tok] = v.x;
            hs[(kq * 4 + 1) * 64 + tok] = v.y;
            hs[(kq * 4 + 2) * 64 + tok] = v.z;
            hs[(kq * 4 + 3) * 64 + tok] = v.w;
        }
        // ---- stage W tile: 128 e x 32 k = 1024 float4 ----
#pragma unroll
        for (int r = 0; r < 4; r++) {
            int q = tid + r * 256;
            int e = q >> 3;
            int kq = q & 7;
            const float* Wp = (e < NEXP) ? (Wl + (size_t)e * DIM)
                                         : (Wn + (size_t)(e - NEXP) * DIM);
            float4 v = *(const float4*)(Wp + kc + kq * 4);
            ws[(kq * 4 + 0) * NOUT + e] = v.x;
            ws[(kq * 4 + 1) * NOUT + e] = v.y;
            ws[(kq * 4 + 2) * NOUT + e] = v.z;
            ws[(kq * 4 + 3) * NOUT + e] = v.w;
        }
        __syncthreads();
#pragma unroll
        for (int kk = 0; kk < KB; kk++) {
            float4 a  = *(const float4*)(hs + kk * 64 + ty * 4);
            float4 b0 = *(const float4*)(ws + kk * NOUT + tx * 8);
            float4 b1 = *(const float4*)(ws + kk * NOUT + tx * 8 + 4);
            float av[4] = {a.x, a.y, a.z, a.w};
            float bv[8] = {b0.x, b0.y, b0.z, b0.w, b1.x, b1.y, b1.z, b1.w};
#pragma unroll
            for (int i = 0; i < 4; i++)
#pragma unroll
                for (int j = 0; j < 8; j++)
                    acc[i][j] = fmaf(av[i], bv[j], acc[i][j]);
        }
        __syncthreads();
    }

    // ---- spill accumulators to LDS as Cs[token][e'] ----
    float* Cs = smem;
#pragma unroll
    for (int i = 0; i < 4; i++)
#pragma unroll
        for (int j = 0; j < 8; j++)
            Cs[(ty * 4 + i) * NOUT + tx * 8 + j] = acc[i][j];
    __syncthreads();

    // ---- epilogue: one wave per token, lane = expert ----
    const int wave = tid >> 6;   // 0..3
    const int lane = tid & 63;   // expert id
    const float blv = bl[lane];
    const float bnv = bn[lane];
    const size_t offIx   = (size_t)M * NEXP;
    const size_t offFull = offIx + (size_t)M * 2;

    for (int t = wave; t < TOK_PER_BLK; t += 4) {
        const int gt = tok0 + t;
        float logit = Cs[t * NOUT + lane] + blv;
        float sraw  = Cs[t * NOUT + NEXP + lane] + bnv;
        // softplus, numerically stable (matches jax.nn.softplus)
        float stdv = fmaxf(sraw, 0.f) + log1pf(expf(-fabsf(sraw)));
        float nz = noise[(size_t)gt * NEXP + lane];
        float noisy = fmaf(nz, stdv, logit);

        // full softmax over 64 lanes
        float m = noisy;
#pragma unroll
        for (int o = 32; o > 0; o >>= 1) m = fmaxf(m, __shfl_xor(m, o, 64));
        float p = __expf(noisy - m) == 0.f ? expf(noisy - m) : expf(noisy - m);
        float s = p;
#pragma unroll
        for (int o = 32; o > 0; o >>= 1) s += __shfl_xor(s, o, 64);
        float fullp = p / s;

        // argmax #1 (ties -> lowest index, matching lax.top_k)
        float v = noisy; int idx = lane;
#pragma unroll
        for (int o = 32; o > 0; o >>= 1) {
            float ov = __shfl_xor(v, o, 64);
            int   oi = __shfl_xor(idx, o, 64);
            if (ov > v || (ov == v && oi < idx)) { v = ov; idx = oi; }
        }
        const float v1 = v; const int i1 = idx;
        // argmax #2
        float nv = (lane == i1) ? -INFINITY : noisy;
        v = nv; idx = lane;
#pragma unroll
        for (int o = 32; o > 0; o >>= 1) {
            float ov = __shfl_xor(v, o, 64);
            int   oi = __shfl_xor(idx, o, 64);
            if (ov > v || (ov == v && oi < idx)) { v = ov; idx = oi; }
        }
        const float v2 = v; const int i2 = idx;

        // sparse softmax over {i1,i2}: max = v1
        float e2 = expf(v2 - v1);
        float den = 1.f + e2;
        float routep = (lane == i1) ? (1.f / den) : ((lane == i2) ? (e2 / den) : 0.f);

        out[(size_t)gt * NEXP + lane] = routep;
        out[offFull + (size_t)gt * NEXP + lane] = fullp;
        if (lane == 0) {
            out[offIx + (size_t)gt * 2 + 0] = (float)i1;
            out[offIx + (size_t)gt * 2 + 1] = (float)i2;
        }
    }
}

extern "C" void kernel_launch(void* const* d_in, const int* in_sizes, int n_in,
                              void* d_out, int out_size, void* d_ws, size_t ws_size,
                              hipStream_t stream) {
    const float* h     = (const float*)d_in[0];
    const float* Wl    = (const float*)d_in[1];
    const float* bl    = (const float*)d_in[2];
    const float* Wn    = (const float*)d_in[3];
    const float* bn    = (const float*)d_in[4];
    const float* noise = (const float*)d_in[5];
    float* out = (float*)d_out;

    const int M = in_sizes[0] / DIM;          // B*S = 32768
    const int grid = M / TOK_PER_BLK;         // 512 blocks

    noisy_topk_router_kernel<<<grid, 256, 0, stream>>>(h, Wl, bl, Wn, bn, noise, out, M);
}

// Round 2
// 314.797 us; speedup vs baseline: 1.0725x; 1.0725x over previous
//
#include <hip/hip_runtime.h>
#include <math.h>

// NoisyTopkRouter: B=8,S=4096,D=1024,E=64,k=2
// Fused GEMM [M,1024] x [1024,128] (Wl ++ Wn) + softplus-noise + softmax + top2.
// fp32 vector-ALU compute (no fp32 MFMA on CDNA4; bf16 would flip top-k order).
// R2: conflict-free LDS staging (lane remap), conflict-free b-reads (expert
// chunk remap: thread tx owns experts 4tx..4tx+3 and 64+4tx..+3), padded
// epilogue stride, register prefetch of next k-tile.

#define DIM 1024
#define NEXP 64
#define NOUT 128
#define TOK_PER_BLK 64
#define KB 32
#define CS 132   // padded Cs row stride (132*4B = 33*16B keeps b128 alignment)

__global__ __launch_bounds__(256, 2)
void noisy_topk_router_kernel(const float* __restrict__ h,
                              const float* __restrict__ Wl,
                              const float* __restrict__ bl,
                              const float* __restrict__ Wn,
                              const float* __restrict__ bn,
                              const float* __restrict__ noise,
                              float* __restrict__ out,
                              int M)
{
    // staging: hs [KB][64] = 2048 f, ws [KB][128] = 4096 f  (24.5 KB)
    // epilogue: Cs [64][132] = 8448 f (33.8 KB)
    __shared__ float smem[TOK_PER_BLK * CS];
    float* hs = smem;
    float* ws = smem + KB * TOK_PER_BLK;

    const int tid = threadIdx.x;
    const int tx = tid & 15;    // expert chunk: e in {4tx..4tx+3} u {64+4tx..}
    const int ty = tid >> 4;    // token quad:   t = ty*4 + i
    const int tok0 = blockIdx.x * TOK_PER_BLK;

    // staging lane maps (consecutive lanes -> consecutive tokens/experts)
    const int h_tok = tid & 63;          // r adds 0 / +4 to kq
    const int h_kq0 = tid >> 6;          // 0..3
    const int w_e   = tid & 127;
    const int w_kq0 = tid >> 7;          // 0..1, r adds 2*r
    const float* Wrow = (w_e < NEXP) ? (Wl + (size_t)w_e * DIM)
                                     : (Wn + (size_t)(w_e - NEXP) * DIM);

    float acc[4][8];
#pragma unroll
    for (int i = 0; i < 4; i++)
#pragma unroll
        for (int j = 0; j < 8; j++) acc[i][j] = 0.f;

    // prefetch registers
    float4 hv[2], wv[4];
    {
        const float* hp = h + (size_t)(tok0 + h_tok) * DIM;
#pragma unroll
        for (int r = 0; r < 2; r++)
            hv[r] = *(const float4*)(hp + (h_kq0 + 4 * r) * 4);
#pragma unroll
        for (int r = 0; r < 4; r++)
            wv[r] = *(const float4*)(Wrow + (w_kq0 + 2 * r) * 4);
    }

    for (int kc = 0; kc < DIM; kc += KB) {
        __syncthreads();   // previous compute done reading LDS
        // ---- store staged tile (conflict-free: consecutive lanes = consecutive banks) ----
#pragma unroll
        for (int r = 0; r < 2; r++) {
            int kq = h_kq0 + 4 * r;
            hs[(kq * 4 + 0) * 64 + h_tok] = hv[r].x;
            hs[(kq * 4 + 1) * 64 + h_tok] = hv[r].y;
            hs[(kq * 4 + 2) * 64 + h_tok] = hv[r].z;
            hs[(kq * 4 + 3) * 64 + h_tok] = hv[r].w;
        }
#pragma unroll
        for (int r = 0; r < 4; r++) {
            int kq = w_kq0 + 2 * r;
            ws[(kq * 4 + 0) * NOUT + w_e] = wv[r].x;
            ws[(kq * 4 + 1) * NOUT + w_e] = wv[r].y;
            ws[(kq * 4 + 2) * NOUT + w_e] = wv[r].z;
            ws[(kq * 4 + 3) * NOUT + w_e] = wv[r].w;
        }
        __syncthreads();

        // ---- prefetch next k-tile (overlaps with FMAs below) ----
        if (kc + KB < DIM) {
            const float* hp = h + (size_t)(tok0 + h_tok) * DIM + kc + KB;
#pragma unroll
            for (int r = 0; r < 2; r++)
                hv[r] = *(const float4*)(hp + (h_kq0 + 4 * r) * 4);
#pragma unroll
            for (int r = 0; r < 4; r++)
                wv[r] = *(const float4*)(Wrow + kc + KB + (w_kq0 + 2 * r) * 4);
        }

        // ---- compute: a broadcast-read (4 distinct rows), b 2-way (free) ----
#pragma unroll
        for (int kk = 0; kk < KB; kk++) {
            float4 a  = *(const float4*)(hs + kk * 64 + ty * 4);
            float4 b0 = *(const float4*)(ws + kk * NOUT + tx * 4);
            float4 b1 = *(const float4*)(ws + kk * NOUT + 64 + tx * 4);
            float av[4] = {a.x, a.y, a.z, a.w};
            float bv[8] = {b0.x, b0.y, b0.z, b0.w, b1.x, b1.y, b1.z, b1.w};
#pragma unroll
            for (int i = 0; i < 4; i++)
#pragma unroll
                for (int j = 0; j < 8; j++)
                    acc[i][j] = fmaf(av[i], bv[j], acc[i][j]);
        }
    }
    __syncthreads();

    // ---- spill accumulators to LDS as Cs[token][e], padded stride ----
    float* Cs = smem;
#pragma unroll
    for (int i = 0; i < 4; i++) {
#pragma unroll
        for (int j = 0; j < 4; j++) {
            Cs[(ty * 4 + i) * CS + tx * 4 + j] = acc[i][j];
            Cs[(ty * 4 + i) * CS + 64 + tx * 4 + j] = acc[i][j + 4];
        }
    }
    __syncthreads();

    // ---- epilogue: one wave per token, lane = expert ----
    const int wave = tid >> 6;   // 0..3
    const int lane = tid & 63;   // expert id
    const float blv = bl[lane];
    const float bnv = bn[lane];
    const size_t offIx   = (size_t)M * NEXP;
    const size_t offFull = offIx + (size_t)M * 2;

    for (int t = wave; t < TOK_PER_BLK; t += 4) {
        const int gt = tok0 + t;
        float logit = Cs[t * CS + lane] + blv;
        float sraw  = Cs[t * CS + 64 + lane] + bnv;
        // softplus (matches jax.nn.softplus)
        float stdv = fmaxf(sraw, 0.f) + log1pf(expf(-fabsf(sraw)));
        float nz = noise[(size_t)gt * NEXP + lane];
        float noisy = fmaf(nz, stdv, logit);

        // full softmax over 64 lanes
        float m = noisy;
#pragma unroll
        for (int o = 32; o > 0; o >>= 1) m = fmaxf(m, __shfl_xor(m, o, 64));
        float p = expf(noisy - m);
        float s = p;
#pragma unroll
        for (int o = 32; o > 0; o >>= 1) s += __shfl_xor(s, o, 64);
        float fullp = p / s;

        // argmax #1 (ties -> lowest index, matching lax.top_k)
        float v = noisy; int idx = lane;
#pragma unroll
        for (int o = 32; o > 0; o >>= 1) {
            float ov = __shfl_xor(v, o, 64);
            int   oi = __shfl_xor(idx, o, 64);
            if (ov > v || (ov == v && oi < idx)) { v = ov; idx = oi; }
        }
        const float v1 = v; const int i1 = idx;
        // argmax #2
        v = (lane == i1) ? -INFINITY : noisy; idx = lane;
#pragma unroll
        for (int o = 32; o > 0; o >>= 1) {
            float ov = __shfl_xor(v, o, 64);
            int   oi = __shfl_xor(idx, o, 64);
            if (ov > v || (ov == v && oi < idx)) { v = ov; idx = oi; }
        }
        const float v2 = v; const int i2 = idx;

        // sparse softmax over {i1,i2}: max = v1
        float e2 = expf(v2 - v1);
        float den = 1.f + e2;
        float routep = (lane == i1) ? (1.f / den) : ((lane == i2) ? (e2 / den) : 0.f);

        out[(size_t)gt * NEXP + lane] = routep;
        out[offFull + (size_t)gt * NEXP + lane] = fullp;
        if (lane == 0) {
            out[offIx + (size_t)gt * 2 + 0] = (float)i1;
            out[offIx + (size_t)gt * 2 + 1] = (float)i2;
        }
    }
}

extern "C" void kernel_launch(void* const* d_in, const int* in_sizes, int n_in,
                              void* d_out, int out_size, void* d_ws, size_t ws_size,
                              hipStream_t stream) {
    const float* h     = (const float*)d_in[0];
    const float* Wl    = (const float*)d_in[1];
    const float* bl    = (const float*)d_in[2];
    const float* Wn    = (const float*)d_in[3];
    const float* bn    = (const float*)d_in[4];
    const float* noise = (const float*)d_in[5];
    float* out = (float*)d_out;

    const int M = in_sizes[0] / DIM;          // B*S = 32768
    const int grid = M / TOK_PER_BLK;         // 512 blocks

    noisy_topk_router_kernel<<<grid, 256, 0, stream>>>(h, Wl, bl, Wn, bn, noise, out, M);
}